// Round 16
// baseline (308.528 us; speedup 1.0000x reference)
//
#include <hip/hip_runtime.h>
#include <hip/hip_bf16.h>
#include <cmath>

typedef __bf16 bf16x8_t __attribute__((ext_vector_type(8)));
typedef float  f32x4_t  __attribute__((ext_vector_type(4)));
using bf16 = __hip_bfloat16;

#define LOG2E 1.44269504088896340736f
#define LN2   0.69314718055994530942f

#define AS1C(p) ((const __attribute__((address_space(1))) void*)(p))
#define AS3C(p) ((__attribute__((address_space(3))) void*)(p))

__device__ __forceinline__ float fexp2(float x) { return __builtin_amdgcn_exp2f(x); }
__device__ __forceinline__ float flog2(float x) { return __builtin_amdgcn_logf(x); }
__device__ __forceinline__ float frcp (float x) { return __builtin_amdgcn_rcpf(x); }

// ---------------------------------------------------------------------------
// Fused multi-tensor f32 -> bf16 cast. 5 segments, one dispatch.
// ---------------------------------------------------------------------------
__global__ __launch_bounds__(256)
void cast_multi(const float* s0, bf16* d0, int e0,
                const float* s1, bf16* d1, int e1,
                const float* s2, bf16* d2, int e2,
                const float* s3, bf16* d3, int e3,
                const float* s4, bf16* d4, int e4)
{
    const int blk = blockIdx.x;
    const float* src; bf16* dst; int base;
    if      (blk < e0) { src = s0; dst = d0; base = blk; }
    else if (blk < e1) { src = s1; dst = d1; base = blk - e0; }
    else if (blk < e2) { src = s2; dst = d2; base = blk - e1; }
    else if (blk < e3) { src = s3; dst = d3; base = blk - e2; }
    else               { src = s4; dst = d4; base = blk - e3; }

    const int i = base * 256 + threadIdx.x;
    const float4* s = (const float4*)(src + (size_t)i * 8);
    float4 a = s[0], b = s[1];
    bf16 o[8];
    o[0] = __float2bfloat16(a.x); o[1] = __float2bfloat16(a.y);
    o[2] = __float2bfloat16(a.z); o[3] = __float2bfloat16(a.w);
    o[4] = __float2bfloat16(b.x); o[5] = __float2bfloat16(b.y);
    o[6] = __float2bfloat16(b.z); o[7] = __float2bfloat16(b.w);
    *(int4*)(dst + (size_t)i * 8) = *(int4*)o;
}

// ---------------------------------------------------------------------------
// bf16 MFMA NT GEMM, BM=64 x BN=128, BK=64, 3-buffer counted-vmcnt pipeline.
// (structure unchanged from round 14)
// ---------------------------------------------------------------------------
template<int MODE, bool SPLITK>
__global__ __launch_bounds__(256)
void gemm_bf16(const bf16* __restrict__ A, const bf16* __restrict__ B,
               float* __restrict__ Cf, bf16* __restrict__ Cb,
               int M, int N, int K, int lda, int ldb, int ldc)
{
    __shared__ __align__(16) bf16 At[3][64][64];
    __shared__ __align__(16) bf16 Bt[3][128][64];

    const int tid  = threadIdx.x;
    const int lane = tid & 63;
    const int wid  = tid >> 6;
    const int wr2  = wid & 1;
    const int wc2  = wid >> 1;
    const int fr   = lane & 15;
    const int fq   = lane >> 4;

    const int row0 = blockIdx.y * 64;
    const int col0 = blockIdx.x * 128;
    const int kb   = SPLITK ? blockIdx.z * K : 0;

    const int lr = lane >> 3;
    const int lh = (lane >> 2) & 1;
    const int lc = lane & 3;

    auto srcA = [&](int rb) {
        const int row = rb + lr;
        const int k = ((lh ^ (row & 1)) * 32) + ((lc ^ ((row >> 1) & 3)) * 8);
        return A + (size_t)(row0 + row) * lda + k + kb;
    };
    auto srcB = [&](int rb) {
        const int row = rb + lr;
        int gr = col0 + row; if (gr >= N) gr = N - 1;
        const int k = ((lh ^ (row & 1)) * 32) + ((lc ^ ((row >> 1) & 3)) * 8);
        return B + (size_t)gr * ldb + k + kb;
    };
    const bf16* aS0 = srcA(wid * 16);
    const bf16* aS1 = srcA(wid * 16 + 8);
    const bf16* bS0 = srcB(wid * 32);
    const bf16* bS1 = srcB(wid * 32 + 8);
    const bf16* bS2 = srcB(wid * 32 + 16);
    const bf16* bS3 = srcB(wid * 32 + 24);

    const int rchunk = (fq ^ ((fr >> 1) & 3)) * 8;
    const int rpar   = fr & 1;
    const int off0   = (rpar)     * 32 + rchunk;
    const int off1   = (rpar ^ 1) * 32 + rchunk;

    f32x4_t acc[2][4];
    #pragma unroll
    for (int m = 0; m < 2; ++m)
        #pragma unroll
        for (int n = 0; n < 4; ++n)
            acc[m][n] = f32x4_t{0.f, 0.f, 0.f, 0.f};

    auto STAGE = [&](int buf, int k0) {
        __builtin_amdgcn_global_load_lds(AS1C(aS0 + k0), AS3C(&At[buf][wid * 16][0]),      16, 0, 0);
        __builtin_amdgcn_global_load_lds(AS1C(aS1 + k0), AS3C(&At[buf][wid * 16 + 8][0]),  16, 0, 0);
        __builtin_amdgcn_global_load_lds(AS1C(bS0 + k0), AS3C(&Bt[buf][wid * 32][0]),      16, 0, 0);
        __builtin_amdgcn_global_load_lds(AS1C(bS1 + k0), AS3C(&Bt[buf][wid * 32 + 8][0]),  16, 0, 0);
        __builtin_amdgcn_global_load_lds(AS1C(bS2 + k0), AS3C(&Bt[buf][wid * 32 + 16][0]), 16, 0, 0);
        __builtin_amdgcn_global_load_lds(AS1C(bS3 + k0), AS3C(&Bt[buf][wid * 32 + 24][0]), 16, 0, 0);
    };

    const int NS = K >> 6;
    STAGE(0, 0);
    if (NS > 1) STAGE(1, 64);

    int cur = 0;
    int sb  = 2;
    for (int t = 0; t < NS; ++t) {
        if (t + 2 < NS) STAGE(sb, (t + 2) << 6);

        if (t + 1 >= NS) {
            asm volatile("s_waitcnt vmcnt(0)" ::: "memory");
        } else if (t + 2 >= NS) {
            asm volatile("s_waitcnt vmcnt(6)" ::: "memory");
        } else {
            asm volatile("s_waitcnt vmcnt(12)" ::: "memory");
        }
        __builtin_amdgcn_sched_barrier(0);
        __builtin_amdgcn_s_barrier();
        __builtin_amdgcn_sched_barrier(0);

        bf16x8_t af0[2], af1[2], bg0[4], bg1[4];
        #pragma unroll
        for (int m = 0; m < 2; ++m) {
            af0[m] = *(const bf16x8_t*)&At[cur][wr2 * 32 + m * 16 + fr][off0];
            af1[m] = *(const bf16x8_t*)&At[cur][wr2 * 32 + m * 16 + fr][off1];
        }
        #pragma unroll
        for (int n = 0; n < 4; ++n) {
            bg0[n] = *(const bf16x8_t*)&Bt[cur][wc2 * 64 + n * 16 + fr][off0];
            bg1[n] = *(const bf16x8_t*)&Bt[cur][wc2 * 64 + n * 16 + fr][off1];
        }
        #pragma unroll
        for (int m = 0; m < 2; ++m)
            #pragma unroll
            for (int n = 0; n < 4; ++n)
                acc[m][n] = __builtin_amdgcn_mfma_f32_16x16x32_bf16(
                    af0[m], bg0[n], acc[m][n], 0, 0, 0);
        #pragma unroll
        for (int m = 0; m < 2; ++m)
            #pragma unroll
            for (int n = 0; n < 4; ++n)
                acc[m][n] = __builtin_amdgcn_mfma_f32_16x16x32_bf16(
                    af1[m], bg1[n], acc[m][n], 0, 0, 0);

        __builtin_amdgcn_sched_barrier(0);
        __builtin_amdgcn_s_barrier();
        __builtin_amdgcn_sched_barrier(0);

        cur = (cur == 2) ? 0 : cur + 1;
        sb  = (sb  == 2) ? 0 : sb  + 1;
    }

    float* Cfz = SPLITK ? (Cf + (size_t)blockIdx.z * M * ldc) : Cf;

    #pragma unroll
    for (int m = 0; m < 2; ++m) {
        #pragma unroll
        for (int n = 0; n < 4; ++n) {
            const int c = col0 + wc2 * 64 + n * 16 + fr;
            if (c < N) {
                #pragma unroll
                for (int r = 0; r < 4; ++r) {
                    const int rr = row0 + wr2 * 32 + m * 16 + fq * 4 + r;
                    if (SPLITK || MODE != 1) Cfz[(size_t)rr * ldc + c] = acc[m][n][r];
                    if (!SPLITK && MODE != 0) Cb[(size_t)rr * ldc + c] = __float2bfloat16(acc[m][n][r]);
                }
            }
        }
    }
}

// ---------------------------------------------------------------------------
// Reduce split-K partials (float4 per thread) -> optional f32 / bf16 outputs.
// ---------------------------------------------------------------------------
__global__ __launch_bounds__(256)
void reduce_pk(const float* __restrict__ part, float* __restrict__ of,
               bf16* __restrict__ oh, int n4, int stride4, int S)
{
    const int i = blockIdx.x * blockDim.x + threadIdx.x;
    if (i >= n4) return;
    const float4* p4 = (const float4*)part;
    float4 s = p4[i];
    for (int k = 1; k < S; ++k) {
        float4 v = p4[(size_t)k * stride4 + i];
        s.x += v.x; s.y += v.y; s.z += v.z; s.w += v.w;
    }
    if (of) ((float4*)of)[i] = s;
    if (oh) {
        bf16 o[4];
        o[0] = __float2bfloat16(s.x); o[1] = __float2bfloat16(s.y);
        o[2] = __float2bfloat16(s.z); o[3] = __float2bfloat16(s.w);
        *(int2*)(oh + (size_t)i * 4) = *(int2*)o;
    }
}

// ---------------------------------------------------------------------------
// Causal depthwise conv1d (width 4) + bias + SiLU, t-tiled by 4.
// ---------------------------------------------------------------------------
__global__ __launch_bounds__(256)
void conv_silu(const bf16* __restrict__ xz, const float* __restrict__ cw,
               const float* __restrict__ cb, bf16* __restrict__ xc,
               int Bsz, int L, int dinner)
{
    const int nv = dinner / 4;
    const int L4 = L / 4;
    const int g  = blockIdx.x * blockDim.x + threadIdx.x;
    const int d4 = (g % nv) * 4;
    const int t4 = (g / nv) % L4;
    const int b  = g / (nv * L4);
    if (b >= Bsz) return;

    const int t0 = t4 * 4;
    const int ldxz = 2 * dinner;

    float4 w0 = *(const float4*)(cw + (size_t)(d4 + 0) * 4);
    float4 w1 = *(const float4*)(cw + (size_t)(d4 + 1) * 4);
    float4 w2 = *(const float4*)(cw + (size_t)(d4 + 2) * 4);
    float4 w3 = *(const float4*)(cw + (size_t)(d4 + 3) * 4);
    float4 bias = *(const float4*)(cb + d4);

    float4 r[7];
    const bf16* base = xz + (size_t)b * L * ldxz + d4;
    #pragma unroll
    for (int k = 0; k < 7; ++k) {
        const int ts = t0 - 3 + k;
        if (ts >= 0 && ts < L) {
            const bf16* rp = base + (size_t)ts * ldxz;
            r[k] = make_float4(__bfloat162float(rp[0]), __bfloat162float(rp[1]),
                               __bfloat162float(rp[2]), __bfloat162float(rp[3]));
        } else {
            r[k] = make_float4(0.f, 0.f, 0.f, 0.f);
        }
    }

    bf16* outp = xc + ((size_t)b * L + t0) * dinner + d4;
    #pragma unroll
    for (int j = 0; j < 4; ++j) {
        float4 acc = bias;
        #pragma unroll
        for (int k = 0; k < 4; ++k) {
            const float4 v = r[j + k];
            acc.x = fmaf(v.x, (&w0.x)[k], acc.x);
            acc.y = fmaf(v.y, (&w1.x)[k], acc.y);
            acc.z = fmaf(v.z, (&w2.x)[k], acc.z);
            acc.w = fmaf(v.w, (&w3.x)[k], acc.w);
        }
        acc.x = acc.x * frcp(1.f + fexp2(-acc.x * LOG2E));
        acc.y = acc.y * frcp(1.f + fexp2(-acc.y * LOG2E));
        acc.z = acc.z * frcp(1.f + fexp2(-acc.z * LOG2E));
        acc.w = acc.w * frcp(1.f + fexp2(-acc.w * LOG2E));
        bf16 o[4];
        o[0] = __float2bfloat16(acc.x); o[1] = __float2bfloat16(acc.y);
        o[2] = __float2bfloat16(acc.z); o[3] = __float2bfloat16(acc.w);
        *(int2*)(outp + (size_t)j * dinner) = *(int2*)o;
    }
}

// ---------------------------------------------------------------------------
// Chunked scan pass 1 (CL template literal, unrolled).
// ---------------------------------------------------------------------------
template<int CL>
__global__ __launch_bounds__(256, 4)
void scan_part1(const bf16* __restrict__ dtraw, const bf16* __restrict__ xc,
                const float* __restrict__ dbl, const float* __restrict__ dtb,
                const float* __restrict__ alog, bf16* __restrict__ hend,
                float* __restrict__ Ssum, int Bsz, int L, int dinner, int NC)
{
    const int g  = blockIdx.x * blockDim.x + threadIdx.x;
    const int s8 = g & 1;
    const int d  = (g >> 1) % dinner;
    const int c  = ((g >> 1) / dinner) % NC;
    const int b  = g / (2 * dinner * NC);
    if (b >= Bsz) return;

    const float* ap = alog + (size_t)d * 16 + s8 * 8;
    float a_[8];
    *(float4*)&a_[0] = *(const float4*)(ap + 0);
    *(float4*)&a_[4] = *(const float4*)(ap + 4);
    float As[8];
    #pragma unroll
    for (int i = 0; i < 8; ++i) As[i] = -fexp2(a_[i] * LOG2E) * LOG2E;
    const float bias = dtb[d];

    const int t0 = c * CL;
    const bf16*  dt_p = dtraw + ((size_t)b * L + t0) * dinner + d;
    const bf16*  xc_p = xc    + ((size_t)b * L + t0) * dinner + d;
    const float* bl_p = dbl   + ((size_t)b * L + t0) * 96 + 64 + s8 * 8;

    float h[8];
    #pragma unroll
    for (int i = 0; i < 8; ++i) h[i] = 0.f;
    float S = 0.f;

    #pragma unroll
    for (int t = 0; t < CL; ++t) {
        const float dtv = __bfloat162float(dt_p[(size_t)t * dinner]);
        const float xcv = __bfloat162float(xc_p[(size_t)t * dinner]);
        float Bv[8];
        *(float4*)&Bv[0] = *(const float4*)(bl_p + t * 96 + 0);
        *(float4*)&Bv[4] = *(const float4*)(bl_p + t * 96 + 4);

        const float xv = dtv + bias;
        const float e  = fexp2(xv * LOG2E);
        const float sp = (xv > 15.f) ? xv : LN2 * flog2(1.f + e);
        S += sp;
        const float u = sp * xcv;
        #pragma unroll
        for (int i = 0; i < 8; ++i)
            h[i] = fmaf(fexp2(sp * As[i]), h[i], u * Bv[i]);
    }

    const size_t idx = ((size_t)b * NC + c) * dinner + d;
    bf16 ho[8];
    #pragma unroll
    for (int i = 0; i < 8; ++i) ho[i] = __float2bfloat16(h[i]);
    *(int4*)(hend + idx * 16 + s8 * 8) = *(int4*)ho;
    if (s8 == 0) Ssum[idx] = S;
}

// ---------------------------------------------------------------------------
// Chunk prefix (NC template literal): replaces hend IN PLACE with the
// EXCLUSIVE prefix state.
// ---------------------------------------------------------------------------
template<int NC>
__global__ __launch_bounds__(256, 4)
void chunk_prefix(bf16* __restrict__ hend, const float* __restrict__ Ssum,
                  const float* __restrict__ alog, int Bsz, int dinner)
{
    const int g = blockIdx.x * blockDim.x + threadIdx.x;
    const int s = g & 15;
    const int d = (g >> 4) % dinner;
    const int b = g / (16 * dinner);
    if (b >= Bsz) return;

    const float As2 = -fexp2(alog[(size_t)d * 16 + s] * LOG2E) * LOG2E;

    size_t idx = (size_t)b * NC * dinner + d;
    float he = __bfloat162float(hend[idx * 16 + s]);
    float Sv = Ssum[idx];
    float h = 0.f;
    #pragma unroll 8
    for (int c = 0; c < NC; ++c) {
        float heN = 0.f, SvN = 0.f;
        if (c + 1 < NC) {
            heN = __bfloat162float(hend[(idx + dinner) * 16 + s]);
            SvN = Ssum[idx + dinner];
        }
        hend[idx * 16 + s] = __float2bfloat16(h);
        h = fmaf(fexp2(As2 * Sv), h, he);
        he = heN; Sv = SvN; idx += dinner;
    }
}

// ---------------------------------------------------------------------------
// Chunked scan pass 2 (CL template literal, unrolled).
// ---------------------------------------------------------------------------
template<int CL>
__global__ __launch_bounds__(256, 4)
void scan_part2(bf16* dty, const bf16* __restrict__ xc,
                const float* __restrict__ dbl, const bf16* __restrict__ xz,
                const float* __restrict__ dtb, const float* __restrict__ alog,
                const float* __restrict__ Dp, const bf16* __restrict__ hinit,
                int Bsz, int L, int dinner, int NC)
{
    const int g  = blockIdx.x * blockDim.x + threadIdx.x;
    const int s8 = g & 1;
    const int d  = (g >> 1) % dinner;
    const int c  = ((g >> 1) / dinner) % NC;
    const int b  = g / (2 * dinner * NC);
    if (b >= Bsz) return;

    const float* ap = alog + (size_t)d * 16 + s8 * 8;
    float a_[8];
    *(float4*)&a_[0] = *(const float4*)(ap + 0);
    *(float4*)&a_[4] = *(const float4*)(ap + 4);
    float As[8];
    #pragma unroll
    for (int i = 0; i < 8; ++i) As[i] = -fexp2(a_[i] * LOG2E) * LOG2E;
    const float bias = dtb[d];
    const float Dval = Dp[d];

    const size_t cidx = ((size_t)b * NC + c) * dinner + d;
    bf16 hi[8];
    *(int4*)hi = *(const int4*)(hinit + cidx * 16 + s8 * 8);
    float h[8];
    #pragma unroll
    for (int i = 0; i < 8; ++i) h[i] = __bfloat162float(hi[i]);

    const int t0 = c * CL;
    bf16*        dt_p = dty + ((size_t)b * L + t0) * dinner + d;
    const bf16*  xc_p = xc  + ((size_t)b * L + t0) * dinner + d;
    const float* bl_p = dbl + ((size_t)b * L + t0) * 96 + 64 + s8 * 8;
    const bf16*  z_p  = xz  + ((size_t)b * L + t0) * (2 * dinner) + dinner + d;

    #pragma unroll
    for (int t = 0; t < CL; ++t) {
        const float dtv = __bfloat162float(dt_p[(size_t)t * dinner]);
        const float xcv = __bfloat162float(xc_p[(size_t)t * dinner]);
        const float zv  = __bfloat162float(z_p[(size_t)t * 2 * dinner]);
        float Bv[8], Cv[8];
        *(float4*)&Bv[0] = *(const float4*)(bl_p + t * 96 + 0);
        *(float4*)&Bv[4] = *(const float4*)(bl_p + t * 96 + 4);
        *(float4*)&Cv[0] = *(const float4*)(bl_p + t * 96 + 16);
        *(float4*)&Cv[4] = *(const float4*)(bl_p + t * 96 + 20);

        const float xv = dtv + bias;
        const float e  = fexp2(xv * LOG2E);
        const float sp = (xv > 15.f) ? xv : LN2 * flog2(1.f + e);
        const float u = sp * xcv;
        float y = 0.f;
        #pragma unroll
        for (int i = 0; i < 8; ++i) {
            h[i] = fmaf(fexp2(sp * As[i]), h[i], u * Bv[i]);
            y = fmaf(h[i], Cv[i], y);
        }
        y += __shfl_xor(y, 1);   // merge the two 8-state halves (lane pair)

        if (s8 == 0) {
            y = fmaf(xcv, Dval, y);
            const float sig = frcp(1.f + fexp2(-zv * LOG2E));
            dt_p[(size_t)t * dinner] = __float2bfloat16(y * (zv * sig));
        }
    }
}

// ---------------------------------------------------------------------------
extern "C" void kernel_launch(void* const* d_in, const int* in_sizes, int n_in,
                              void* d_out, int out_size, void* d_ws, size_t ws_size,
                              hipStream_t stream)
{
    const float* x    = (const float*)d_in[0];
    const float* inw  = (const float*)d_in[1];
    const float* cw   = (const float*)d_in[2];
    const float* cb   = (const float*)d_in[3];
    const float* xw   = (const float*)d_in[4];
    const float* dtw  = (const float*)d_in[5];
    const float* dtb  = (const float*)d_in[6];
    const float* alog = (const float*)d_in[7];
    const float* Dp   = (const float*)d_in[8];
    const float* ow   = (const float*)d_in[9];
    float* out = (float*)d_out;

    const int Bsz = 2, L = 1024, dmodel = 1024, dinner = 2048;
    const int BL = Bsz * L;            // 2048
    const int NC = 64;                 // 64 chunks of CL=16 (template literal)
    const int SPX = 16, KSX = dinner / SPX;   // x_proj split-K

    // --- workspace layout ---------------------------------------------------
    char* p = (char*)d_ws;
    auto alloc = [&](size_t bytes) { char* r = p; p += (bytes + 63) & ~size_t(63); return r; };
    bf16*  wb_in  = (bf16*) alloc((size_t)2 * 2 * dinner * dmodel * 2);   // both layers
    bf16*  wb_x   = (bf16*) alloc((size_t)2 * 96 * dinner * 2);
    bf16*  wb_dt  = (bf16*) alloc((size_t)2 * dinner * 64 * 2);
    bf16*  wb_ow  = (bf16*) alloc((size_t)2 * dmodel * dinner * 2);
    bf16*  curb   = (bf16*) alloc((size_t)BL * dmodel * 2);
    bf16*  xzb16  = (bf16*) alloc((size_t)BL * 2 * dinner * 2);
    bf16*  xcb16  = (bf16*) alloc((size_t)BL * dinner * 2);
    float* dblb   = (float*)alloc((size_t)BL * 96 * 4);
    bf16*  dblb16 = (bf16*) alloc((size_t)BL * 96 * 2);
    bf16*  dtrb16 = (bf16*) alloc((size_t)BL * dinner * 2);
    float* ssumb  = (float*)alloc((size_t)Bsz * NC * dinner * 4);
    // partb (x_proj partials, 12.6 MB max) is dead during the scan;
    // hendb bf16 (8.4 MB) aliases it.
    float* partb  = (float*)alloc((size_t)SPX * BL * 96 * 4);
    bf16*  hendb  = (bf16*)partb;

    const int scan_blocks = (Bsz * NC * dinner * 2) / 256;    // 2048
    const int pfx_blocks  = (Bsz * dinner * 16) / 256;        // 256

    // ---- one fused cast dispatch (input + all weights, both layers) --------
    {
        const int n8_x  = BL * dmodel / 8;
        const int n8_in = 2 * 2 * dinner * dmodel / 8;
        const int n8_xw = 2 * 96 * dinner / 8;
        const int n8_dt = 2 * dinner * 64 / 8;
        const int n8_ow = 2 * dmodel * dinner / 8;
        const int e0 = n8_x / 256;
        const int e1 = e0 + n8_in / 256;
        const int e2 = e1 + n8_xw / 256;
        const int e3 = e2 + n8_dt / 256;
        const int e4 = e3 + n8_ow / 256;
        cast_multi<<<e4, 256, 0, stream>>>(
            x, curb, e0, inw, wb_in, e1, xw, wb_x, e2, dtw, wb_dt, e3, ow, wb_ow, e4);
    }

    for (int l = 0; l < 2; ++l) {
        const bf16*  wb_in_l = wb_in + (size_t)l * 2 * dinner * dmodel;
        const bf16*  wb_x_l  = wb_x  + (size_t)l * 96 * dinner;
        const bf16*  wb_dt_l = wb_dt + (size_t)l * dinner * 64;
        const bf16*  wb_ow_l = wb_ow + (size_t)l * dmodel * dinner;
        const float* cw_l    = cw   + (size_t)l * dinner * 4;
        const float* cb_l    = cb   + (size_t)l * dinner;
        const float* dtb_l   = dtb  + (size_t)l * dinner;
        const float* alog_l  = alog + (size_t)l * dinner * 16;
        const float* Dp_l    = Dp   + (size_t)l * dinner;

        // 1) xz = cur @ in_w^T   (2048 x 4096, K=1024) -> bf16; 1024 blocks
        gemm_bf16<1, false><<<dim3(2 * dinner / 128, BL / 64), 256, 0, stream>>>(
            curb, wb_in_l, nullptr, xzb16, BL, 2 * dinner, dmodel, dmodel, dmodel, 2 * dinner);

        // 2) xc = silu(conv(xr) + cb) -> bf16 (t-tiled by 4)
        conv_silu<<<(Bsz * (L / 4) * (dinner / 4)) / 256, 256, 0, stream>>>(
            xzb16, cw_l, cb_l, xcb16, Bsz, L, dinner);

        // 3) dbl = xc @ xw^T     (2048 x 96, K=2048), split-K x16 + reduce
        gemm_bf16<0, true><<<dim3(1, BL / 64, SPX), 256, 0, stream>>>(
            xcb16, wb_x_l, partb, nullptr, BL, 96, KSX, dinner, dinner, 96);
        reduce_pk<<<(BL * 96 / 4 + 255) / 256, 256, 0, stream>>>(
            partb, dblb, dblb16, BL * 96 / 4, BL * 96 / 4, SPX);

        // 4) dt_raw = dbl[:, :64] @ dtw^T  (2048 x 2048, K=64) -> bf16
        gemm_bf16<1, false><<<dim3(dinner / 128, BL / 64), 256, 0, stream>>>(
            dblb16, wb_dt_l, nullptr, dtrb16, BL, dinner, 64, 96, 64, dinner);

        // 5) chunked scan: local scans -> chunk prefix -> final pass
        scan_part1<16><<<scan_blocks, 256, 0, stream>>>(
            dtrb16, xcb16, dblb, dtb_l, alog_l, hendb, ssumb, Bsz, L, dinner, NC);
        chunk_prefix<64><<<pfx_blocks, 256, 0, stream>>>(
            hendb, ssumb, alog_l, Bsz, dinner);
        scan_part2<16><<<scan_blocks, 256, 0, stream>>>(
            dtrb16, xcb16, dblb, xzb16, dtb_l, alog_l, Dp_l, hendb,
            Bsz, L, dinner, NC);

        // 6) out = y @ ow^T      (2048 x 1024, K=2048), DIRECT (no split-K):
        //    3-buffer pipeline covers latency; epilogue stores straight to
        //    curb (bf16, l=0) or out (f32, l=1). Removes 2 reduce dispatches
        //    + 33 MB of partial round-trip per run.
        if (l == 0)
            gemm_bf16<1, false><<<dim3(dmodel / 128, BL / 64), 256, 0, stream>>>(
                dtrb16, wb_ow_l, nullptr, curb, BL, dmodel, dinner, dinner, dinner, dmodel);
        else
            gemm_bf16<0, false><<<dim3(dmodel / 128, BL / 64), 256, 0, stream>>>(
                dtrb16, wb_ow_l, out, nullptr, BL, dmodel, dinner, dinner, dinner, dmodel);
    }
}

// Round 17
// 297.764 us; speedup vs baseline: 1.0362x; 1.0362x over previous
//
#include <hip/hip_runtime.h>
#include <hip/hip_bf16.h>
#include <cmath>

typedef __bf16 bf16x8_t __attribute__((ext_vector_type(8)));
typedef float  f32x4_t  __attribute__((ext_vector_type(4)));
using bf16 = __hip_bfloat16;

#define LOG2E 1.44269504088896340736f
#define LN2   0.69314718055994530942f

#define AS1C(p) ((const __attribute__((address_space(1))) void*)(p))
#define AS3C(p) ((__attribute__((address_space(3))) void*)(p))

__device__ __forceinline__ float fexp2(float x) { return __builtin_amdgcn_exp2f(x); }
__device__ __forceinline__ float flog2(float x) { return __builtin_amdgcn_logf(x); }
__device__ __forceinline__ float frcp (float x) { return __builtin_amdgcn_rcpf(x); }

// ---------------------------------------------------------------------------
// Fused multi-tensor f32 -> bf16 cast. 5 segments, one dispatch.
// ---------------------------------------------------------------------------
__global__ __launch_bounds__(256)
void cast_multi(const float* s0, bf16* d0, int e0,
                const float* s1, bf16* d1, int e1,
                const float* s2, bf16* d2, int e2,
                const float* s3, bf16* d3, int e3,
                const float* s4, bf16* d4, int e4)
{
    const int blk = blockIdx.x;
    const float* src; bf16* dst; int base;
    if      (blk < e0) { src = s0; dst = d0; base = blk; }
    else if (blk < e1) { src = s1; dst = d1; base = blk - e0; }
    else if (blk < e2) { src = s2; dst = d2; base = blk - e1; }
    else if (blk < e3) { src = s3; dst = d3; base = blk - e2; }
    else               { src = s4; dst = d4; base = blk - e3; }

    const int i = base * 256 + threadIdx.x;
    const float4* s = (const float4*)(src + (size_t)i * 8);
    float4 a = s[0], b = s[1];
    bf16 o[8];
    o[0] = __float2bfloat16(a.x); o[1] = __float2bfloat16(a.y);
    o[2] = __float2bfloat16(a.z); o[3] = __float2bfloat16(a.w);
    o[4] = __float2bfloat16(b.x); o[5] = __float2bfloat16(b.y);
    o[6] = __float2bfloat16(b.z); o[7] = __float2bfloat16(b.w);
    *(int4*)(dst + (size_t)i * 8) = *(int4*)o;
}

// ---------------------------------------------------------------------------
// bf16 MFMA NT GEMM, BM=64 x BN=128, BK=64, 3-buffer counted-vmcnt pipeline.
// SPLITK: blockIdx.z = K-segment; f32 partial to Cf + z*M*ldc.
// MODE: 0 = f32 store, 1 = bf16 store (ignored when SPLITK).
// ---------------------------------------------------------------------------
template<int MODE, bool SPLITK>
__global__ __launch_bounds__(256)
void gemm_bf16(const bf16* __restrict__ A, const bf16* __restrict__ B,
               float* __restrict__ Cf, bf16* __restrict__ Cb,
               int M, int N, int K, int lda, int ldb, int ldc)
{
    __shared__ __align__(16) bf16 At[3][64][64];
    __shared__ __align__(16) bf16 Bt[3][128][64];

    const int tid  = threadIdx.x;
    const int lane = tid & 63;
    const int wid  = tid >> 6;
    const int wr2  = wid & 1;
    const int wc2  = wid >> 1;
    const int fr   = lane & 15;
    const int fq   = lane >> 4;

    const int row0 = blockIdx.y * 64;
    const int col0 = blockIdx.x * 128;
    const int kb   = SPLITK ? blockIdx.z * K : 0;

    const int lr = lane >> 3;
    const int lh = (lane >> 2) & 1;
    const int lc = lane & 3;

    auto srcA = [&](int rb) {
        const int row = rb + lr;
        const int k = ((lh ^ (row & 1)) * 32) + ((lc ^ ((row >> 1) & 3)) * 8);
        return A + (size_t)(row0 + row) * lda + k + kb;
    };
    auto srcB = [&](int rb) {
        const int row = rb + lr;
        int gr = col0 + row; if (gr >= N) gr = N - 1;
        const int k = ((lh ^ (row & 1)) * 32) + ((lc ^ ((row >> 1) & 3)) * 8);
        return B + (size_t)gr * ldb + k + kb;
    };
    const bf16* aS0 = srcA(wid * 16);
    const bf16* aS1 = srcA(wid * 16 + 8);
    const bf16* bS0 = srcB(wid * 32);
    const bf16* bS1 = srcB(wid * 32 + 8);
    const bf16* bS2 = srcB(wid * 32 + 16);
    const bf16* bS3 = srcB(wid * 32 + 24);

    const int rchunk = (fq ^ ((fr >> 1) & 3)) * 8;
    const int rpar   = fr & 1;
    const int off0   = (rpar)     * 32 + rchunk;
    const int off1   = (rpar ^ 1) * 32 + rchunk;

    f32x4_t acc[2][4];
    #pragma unroll
    for (int m = 0; m < 2; ++m)
        #pragma unroll
        for (int n = 0; n < 4; ++n)
            acc[m][n] = f32x4_t{0.f, 0.f, 0.f, 0.f};

    auto STAGE = [&](int buf, int k0) {
        __builtin_amdgcn_global_load_lds(AS1C(aS0 + k0), AS3C(&At[buf][wid * 16][0]),      16, 0, 0);
        __builtin_amdgcn_global_load_lds(AS1C(aS1 + k0), AS3C(&At[buf][wid * 16 + 8][0]),  16, 0, 0);
        __builtin_amdgcn_global_load_lds(AS1C(bS0 + k0), AS3C(&Bt[buf][wid * 32][0]),      16, 0, 0);
        __builtin_amdgcn_global_load_lds(AS1C(bS1 + k0), AS3C(&Bt[buf][wid * 32 + 8][0]),  16, 0, 0);
        __builtin_amdgcn_global_load_lds(AS1C(bS2 + k0), AS3C(&Bt[buf][wid * 32 + 16][0]), 16, 0, 0);
        __builtin_amdgcn_global_load_lds(AS1C(bS3 + k0), AS3C(&Bt[buf][wid * 32 + 24][0]), 16, 0, 0);
    };

    const int NS = K >> 6;
    STAGE(0, 0);
    if (NS > 1) STAGE(1, 64);

    int cur = 0;
    int sb  = 2;
    for (int t = 0; t < NS; ++t) {
        if (t + 2 < NS) STAGE(sb, (t + 2) << 6);

        if (t + 1 >= NS) {
            asm volatile("s_waitcnt vmcnt(0)" ::: "memory");
        } else if (t + 2 >= NS) {
            asm volatile("s_waitcnt vmcnt(6)" ::: "memory");
        } else {
            asm volatile("s_waitcnt vmcnt(12)" ::: "memory");
        }
        __builtin_amdgcn_sched_barrier(0);
        __builtin_amdgcn_s_barrier();
        __builtin_amdgcn_sched_barrier(0);

        bf16x8_t af0[2], af1[2], bg0[4], bg1[4];
        #pragma unroll
        for (int m = 0; m < 2; ++m) {
            af0[m] = *(const bf16x8_t*)&At[cur][wr2 * 32 + m * 16 + fr][off0];
            af1[m] = *(const bf16x8_t*)&At[cur][wr2 * 32 + m * 16 + fr][off1];
        }
        #pragma unroll
        for (int n = 0; n < 4; ++n) {
            bg0[n] = *(const bf16x8_t*)&Bt[cur][wc2 * 64 + n * 16 + fr][off0];
            bg1[n] = *(const bf16x8_t*)&Bt[cur][wc2 * 64 + n * 16 + fr][off1];
        }
        #pragma unroll
        for (int m = 0; m < 2; ++m)
            #pragma unroll
            for (int n = 0; n < 4; ++n)
                acc[m][n] = __builtin_amdgcn_mfma_f32_16x16x32_bf16(
                    af0[m], bg0[n], acc[m][n], 0, 0, 0);
        #pragma unroll
        for (int m = 0; m < 2; ++m)
            #pragma unroll
            for (int n = 0; n < 4; ++n)
                acc[m][n] = __builtin_amdgcn_mfma_f32_16x16x32_bf16(
                    af1[m], bg1[n], acc[m][n], 0, 0, 0);

        __builtin_amdgcn_sched_barrier(0);
        __builtin_amdgcn_s_barrier();
        __builtin_amdgcn_sched_barrier(0);

        cur = (cur == 2) ? 0 : cur + 1;
        sb  = (sb  == 2) ? 0 : sb  + 1;
    }

    float* Cfz = SPLITK ? (Cf + (size_t)blockIdx.z * M * ldc) : Cf;

    #pragma unroll
    for (int m = 0; m < 2; ++m) {
        #pragma unroll
        for (int n = 0; n < 4; ++n) {
            const int c = col0 + wc2 * 64 + n * 16 + fr;
            if (c < N) {
                #pragma unroll
                for (int r = 0; r < 4; ++r) {
                    const int rr = row0 + wr2 * 32 + m * 16 + fq * 4 + r;
                    if (SPLITK || MODE != 1) Cfz[(size_t)rr * ldc + c] = acc[m][n][r];
                    if (!SPLITK && MODE != 0) Cb[(size_t)rr * ldc + c] = __float2bfloat16(acc[m][n][r]);
                }
            }
        }
    }
}

// ---------------------------------------------------------------------------
// Reduce split-K partials (float4 per thread) -> optional f32 / bf16 outputs.
// ---------------------------------------------------------------------------
__global__ __launch_bounds__(256)
void reduce_pk(const float* __restrict__ part, float* __restrict__ of,
               bf16* __restrict__ oh, int n4, int stride4, int S)
{
    const int i = blockIdx.x * blockDim.x + threadIdx.x;
    if (i >= n4) return;
    const float4* p4 = (const float4*)part;
    float4 s = p4[i];
    for (int k = 1; k < S; ++k) {
        float4 v = p4[(size_t)k * stride4 + i];
        s.x += v.x; s.y += v.y; s.z += v.z; s.w += v.w;
    }
    if (of) ((float4*)of)[i] = s;
    if (oh) {
        bf16 o[4];
        o[0] = __float2bfloat16(s.x); o[1] = __float2bfloat16(s.y);
        o[2] = __float2bfloat16(s.z); o[3] = __float2bfloat16(s.w);
        *(int2*)(oh + (size_t)i * 4) = *(int2*)o;
    }
}

// ---------------------------------------------------------------------------
// Causal depthwise conv1d (width 4) + bias + SiLU, t-tiled by 4.
// ---------------------------------------------------------------------------
__global__ __launch_bounds__(256)
void conv_silu(const bf16* __restrict__ xz, const float* __restrict__ cw,
               const float* __restrict__ cb, bf16* __restrict__ xc,
               int Bsz, int L, int dinner)
{
    const int nv = dinner / 4;
    const int L4 = L / 4;
    const int g  = blockIdx.x * blockDim.x + threadIdx.x;
    const int d4 = (g % nv) * 4;
    const int t4 = (g / nv) % L4;
    const int b  = g / (nv * L4);
    if (b >= Bsz) return;

    const int t0 = t4 * 4;
    const int ldxz = 2 * dinner;

    float4 w0 = *(const float4*)(cw + (size_t)(d4 + 0) * 4);
    float4 w1 = *(const float4*)(cw + (size_t)(d4 + 1) * 4);
    float4 w2 = *(const float4*)(cw + (size_t)(d4 + 2) * 4);
    float4 w3 = *(const float4*)(cw + (size_t)(d4 + 3) * 4);
    float4 bias = *(const float4*)(cb + d4);

    float4 r[7];
    const bf16* base = xz + (size_t)b * L * ldxz + d4;
    #pragma unroll
    for (int k = 0; k < 7; ++k) {
        const int ts = t0 - 3 + k;
        if (ts >= 0 && ts < L) {
            const bf16* rp = base + (size_t)ts * ldxz;
            r[k] = make_float4(__bfloat162float(rp[0]), __bfloat162float(rp[1]),
                               __bfloat162float(rp[2]), __bfloat162float(rp[3]));
        } else {
            r[k] = make_float4(0.f, 0.f, 0.f, 0.f);
        }
    }

    bf16* outp = xc + ((size_t)b * L + t0) * dinner + d4;
    #pragma unroll
    for (int j = 0; j < 4; ++j) {
        float4 acc = bias;
        #pragma unroll
        for (int k = 0; k < 4; ++k) {
            const float4 v = r[j + k];
            acc.x = fmaf(v.x, (&w0.x)[k], acc.x);
            acc.y = fmaf(v.y, (&w1.x)[k], acc.y);
            acc.z = fmaf(v.z, (&w2.x)[k], acc.z);
            acc.w = fmaf(v.w, (&w3.x)[k], acc.w);
        }
        acc.x = acc.x * frcp(1.f + fexp2(-acc.x * LOG2E));
        acc.y = acc.y * frcp(1.f + fexp2(-acc.y * LOG2E));
        acc.z = acc.z * frcp(1.f + fexp2(-acc.z * LOG2E));
        acc.w = acc.w * frcp(1.f + fexp2(-acc.w * LOG2E));
        bf16 o[4];
        o[0] = __float2bfloat16(acc.x); o[1] = __float2bfloat16(acc.y);
        o[2] = __float2bfloat16(acc.z); o[3] = __float2bfloat16(acc.w);
        *(int2*)(outp + (size_t)j * dinner) = *(int2*)o;
    }
}

// ---------------------------------------------------------------------------
// Chunked scan pass 1 (CL template literal, unrolled t-loop).
// Thread = (b, chunk, d, half) owning 8 states.
// ---------------------------------------------------------------------------
template<int CL>
__global__ __launch_bounds__(256, 4)
void scan_part1(const bf16* __restrict__ dtraw, const bf16* __restrict__ xc,
                const float* __restrict__ dbl, const float* __restrict__ dtb,
                const float* __restrict__ alog, bf16* __restrict__ hend,
                float* __restrict__ Ssum, int Bsz, int L, int dinner, int NC)
{
    const int g  = blockIdx.x * blockDim.x + threadIdx.x;
    const int s8 = g & 1;
    const int d  = (g >> 1) % dinner;
    const int c  = ((g >> 1) / dinner) % NC;
    const int b  = g / (2 * dinner * NC);
    if (b >= Bsz) return;

    const float* ap = alog + (size_t)d * 16 + s8 * 8;
    float a_[8];
    *(float4*)&a_[0] = *(const float4*)(ap + 0);
    *(float4*)&a_[4] = *(const float4*)(ap + 4);
    float As[8];
    #pragma unroll
    for (int i = 0; i < 8; ++i) As[i] = -fexp2(a_[i] * LOG2E) * LOG2E;
    const float bias = dtb[d];

    const int t0 = c * CL;
    const bf16*  dt_p = dtraw + ((size_t)b * L + t0) * dinner + d;
    const bf16*  xc_p = xc    + ((size_t)b * L + t0) * dinner + d;
    const float* bl_p = dbl   + ((size_t)b * L + t0) * 96 + 64 + s8 * 8;

    float h[8];
    #pragma unroll
    for (int i = 0; i < 8; ++i) h[i] = 0.f;
    float S = 0.f;

    #pragma unroll
    for (int t = 0; t < CL; ++t) {
        const float dtv = __bfloat162float(dt_p[(size_t)t * dinner]);
        const float xcv = __bfloat162float(xc_p[(size_t)t * dinner]);
        float Bv[8];
        *(float4*)&Bv[0] = *(const float4*)(bl_p + t * 96 + 0);
        *(float4*)&Bv[4] = *(const float4*)(bl_p + t * 96 + 4);

        const float xv = dtv + bias;
        const float e  = fexp2(xv * LOG2E);
        const float sp = (xv > 15.f) ? xv : LN2 * flog2(1.f + e);
        S += sp;
        const float u = sp * xcv;
        #pragma unroll
        for (int i = 0; i < 8; ++i)
            h[i] = fmaf(fexp2(sp * As[i]), h[i], u * Bv[i]);
    }

    const size_t idx = ((size_t)b * NC + c) * dinner + d;
    bf16 ho[8];
    #pragma unroll
    for (int i = 0; i < 8; ++i) ho[i] = __float2bfloat16(h[i]);
    *(int4*)(hend + idx * 16 + s8 * 8) = *(int4*)ho;
    if (s8 == 0) Ssum[idx] = S;
}

// ---------------------------------------------------------------------------
// Chunk prefix (NC template literal): replaces hend IN PLACE with the
// EXCLUSIVE prefix state.
// ---------------------------------------------------------------------------
template<int NC>
__global__ __launch_bounds__(256, 4)
void chunk_prefix(bf16* __restrict__ hend, const float* __restrict__ Ssum,
                  const float* __restrict__ alog, int Bsz, int dinner)
{
    const int g = blockIdx.x * blockDim.x + threadIdx.x;
    const int s = g & 15;
    const int d = (g >> 4) % dinner;
    const int b = g / (16 * dinner);
    if (b >= Bsz) return;

    const float As2 = -fexp2(alog[(size_t)d * 16 + s] * LOG2E) * LOG2E;

    size_t idx = (size_t)b * NC * dinner + d;
    float he = __bfloat162float(hend[idx * 16 + s]);
    float Sv = Ssum[idx];
    float h = 0.f;
    #pragma unroll 8
    for (int c = 0; c < NC; ++c) {
        float heN = 0.f, SvN = 0.f;
        if (c + 1 < NC) {
            heN = __bfloat162float(hend[(idx + dinner) * 16 + s]);
            SvN = Ssum[idx + dinner];
        }
        hend[idx * 16 + s] = __float2bfloat16(h);
        h = fmaf(fexp2(As2 * Sv), h, he);
        he = heN; Sv = SvN; idx += dinner;
    }
}

// ---------------------------------------------------------------------------
// Chunked scan pass 2 (CL template literal, unrolled t-loop).
// ---------------------------------------------------------------------------
template<int CL>
__global__ __launch_bounds__(256, 4)
void scan_part2(bf16* dty, const bf16* __restrict__ xc,
                const float* __restrict__ dbl, const bf16* __restrict__ xz,
                const float* __restrict__ dtb, const float* __restrict__ alog,
                const float* __restrict__ Dp, const bf16* __restrict__ hinit,
                int Bsz, int L, int dinner, int NC)
{
    const int g  = blockIdx.x * blockDim.x + threadIdx.x;
    const int s8 = g & 1;
    const int d  = (g >> 1) % dinner;
    const int c  = ((g >> 1) / dinner) % NC;
    const int b  = g / (2 * dinner * NC);
    if (b >= Bsz) return;

    const float* ap = alog + (size_t)d * 16 + s8 * 8;
    float a_[8];
    *(float4*)&a_[0] = *(const float4*)(ap + 0);
    *(float4*)&a_[4] = *(const float4*)(ap + 4);
    float As[8];
    #pragma unroll
    for (int i = 0; i < 8; ++i) As[i] = -fexp2(a_[i] * LOG2E) * LOG2E;
    const float bias = dtb[d];
    const float Dval = Dp[d];

    const size_t cidx = ((size_t)b * NC + c) * dinner + d;
    bf16 hi[8];
    *(int4*)hi = *(const int4*)(hinit + cidx * 16 + s8 * 8);
    float h[8];
    #pragma unroll
    for (int i = 0; i < 8; ++i) h[i] = __bfloat162float(hi[i]);

    const int t0 = c * CL;
    bf16*        dt_p = dty + ((size_t)b * L + t0) * dinner + d;
    const bf16*  xc_p = xc  + ((size_t)b * L + t0) * dinner + d;
    const float* bl_p = dbl + ((size_t)b * L + t0) * 96 + 64 + s8 * 8;
    const bf16*  z_p  = xz  + ((size_t)b * L + t0) * (2 * dinner) + dinner + d;

    #pragma unroll
    for (int t = 0; t < CL; ++t) {
        const float dtv = __bfloat162float(dt_p[(size_t)t * dinner]);
        const float xcv = __bfloat162float(xc_p[(size_t)t * dinner]);
        const float zv  = __bfloat162float(z_p[(size_t)t * 2 * dinner]);
        float Bv[8], Cv[8];
        *(float4*)&Bv[0] = *(const float4*)(bl_p + t * 96 + 0);
        *(float4*)&Bv[4] = *(const float4*)(bl_p + t * 96 + 4);
        *(float4*)&Cv[0] = *(const float4*)(bl_p + t * 96 + 16);
        *(float4*)&Cv[4] = *(const float4*)(bl_p + t * 96 + 20);

        const float xv = dtv + bias;
        const float e  = fexp2(xv * LOG2E);
        const float sp = (xv > 15.f) ? xv : LN2 * flog2(1.f + e);
        const float u = sp * xcv;
        float y = 0.f;
        #pragma unroll
        for (int i = 0; i < 8; ++i) {
            h[i] = fmaf(fexp2(sp * As[i]), h[i], u * Bv[i]);
            y = fmaf(h[i], Cv[i], y);
        }
        y += __shfl_xor(y, 1);   // merge the two 8-state halves (lane pair)

        if (s8 == 0) {
            y = fmaf(xcv, Dval, y);
            const float sig = frcp(1.f + fexp2(-zv * LOG2E));
            dt_p[(size_t)t * dinner] = __float2bfloat16(y * (zv * sig));
        }
    }
}

// ---------------------------------------------------------------------------
extern "C" void kernel_launch(void* const* d_in, const int* in_sizes, int n_in,
                              void* d_out, int out_size, void* d_ws, size_t ws_size,
                              hipStream_t stream)
{
    const float* x    = (const float*)d_in[0];
    const float* inw  = (const float*)d_in[1];
    const float* cw   = (const float*)d_in[2];
    const float* cb   = (const float*)d_in[3];
    const float* xw   = (const float*)d_in[4];
    const float* dtw  = (const float*)d_in[5];
    const float* dtb  = (const float*)d_in[6];
    const float* alog = (const float*)d_in[7];
    const float* Dp   = (const float*)d_in[8];
    const float* ow   = (const float*)d_in[9];
    float* out = (float*)d_out;

    const int Bsz = 2, L = 1024, dmodel = 1024, dinner = 2048;
    const int BL = Bsz * L;            // 2048
    const int NC = 64;                 // 64 chunks of CL=16 (template literal)
    const int SPX = 16, KSX = dinner / SPX;   // x_proj split-K
    const int SPO = 2,  KSO = dinner / SPO;   // out_proj split-K

    // --- workspace layout ---------------------------------------------------
    char* p = (char*)d_ws;
    auto alloc = [&](size_t bytes) { char* r = p; p += (bytes + 63) & ~size_t(63); return r; };
    bf16*  wb_in  = (bf16*) alloc((size_t)2 * 2 * dinner * dmodel * 2);   // both layers
    bf16*  wb_x   = (bf16*) alloc((size_t)2 * 96 * dinner * 2);
    bf16*  wb_dt  = (bf16*) alloc((size_t)2 * dinner * 64 * 2);
    bf16*  wb_ow  = (bf16*) alloc((size_t)2 * dmodel * dinner * 2);
    bf16*  curb   = (bf16*) alloc((size_t)BL * dmodel * 2);
    bf16*  xzb16  = (bf16*) alloc((size_t)BL * 2 * dinner * 2);
    bf16*  xcb16  = (bf16*) alloc((size_t)BL * dinner * 2);
    float* dblb   = (float*)alloc((size_t)BL * 96 * 4);
    bf16*  dblb16 = (bf16*) alloc((size_t)BL * 96 * 2);
    bf16*  dtrb16 = (bf16*) alloc((size_t)BL * dinner * 2);
    float* ssumb  = (float*)alloc((size_t)Bsz * NC * dinner * 4);
    // partb (16.8 MB) is dead during the scan; hendb bf16 (8.4 MB) aliases it.
    float* partb  = (float*)alloc((size_t)SPO * BL * dmodel * 4);
    bf16*  hendb  = (bf16*)partb;

    const int scan_blocks = (Bsz * NC * dinner * 2) / 256;    // 2048
    const int pfx_blocks  = (Bsz * dinner * 16) / 256;        // 256

    // ---- one fused cast dispatch (input + all weights, both layers) --------
    {
        const int n8_x  = BL * dmodel / 8;
        const int n8_in = 2 * 2 * dinner * dmodel / 8;
        const int n8_xw = 2 * 96 * dinner / 8;
        const int n8_dt = 2 * dinner * 64 / 8;
        const int n8_ow = 2 * dmodel * dinner / 8;
        const int e0 = n8_x / 256;
        const int e1 = e0 + n8_in / 256;
        const int e2 = e1 + n8_xw / 256;
        const int e3 = e2 + n8_dt / 256;
        const int e4 = e3 + n8_ow / 256;
        cast_multi<<<e4, 256, 0, stream>>>(
            x, curb, e0, inw, wb_in, e1, xw, wb_x, e2, dtw, wb_dt, e3, ow, wb_ow, e4);
    }

    for (int l = 0; l < 2; ++l) {
        const bf16*  wb_in_l = wb_in + (size_t)l * 2 * dinner * dmodel;
        const bf16*  wb_x_l  = wb_x  + (size_t)l * 96 * dinner;
        const bf16*  wb_dt_l = wb_dt + (size_t)l * dinner * 64;
        const bf16*  wb_ow_l = wb_ow + (size_t)l * dmodel * dinner;
        const float* cw_l    = cw   + (size_t)l * dinner * 4;
        const float* cb_l    = cb   + (size_t)l * dinner;
        const float* dtb_l   = dtb  + (size_t)l * dinner;
        const float* alog_l  = alog + (size_t)l * dinner * 16;
        const float* Dp_l    = Dp   + (size_t)l * dinner;

        // 1) xz = cur @ in_w^T   (2048 x 4096, K=1024) -> bf16; 1024 blocks
        gemm_bf16<1, false><<<dim3(2 * dinner / 128, BL / 64), 256, 0, stream>>>(
            curb, wb_in_l, nullptr, xzb16, BL, 2 * dinner, dmodel, dmodel, dmodel, 2 * dinner);

        // 2) xc = silu(conv(xr) + cb) -> bf16 (t-tiled by 4)
        conv_silu<<<(Bsz * (L / 4) * (dinner / 4)) / 256, 256, 0, stream>>>(
            xzb16, cw_l, cb_l, xcb16, Bsz, L, dinner);

        // 3) dbl = xc @ xw^T     (2048 x 96, K=2048), split-K x16 + reduce
        gemm_bf16<0, true><<<dim3(1, BL / 64, SPX), 256, 0, stream>>>(
            xcb16, wb_x_l, partb, nullptr, BL, 96, KSX, dinner, dinner, 96);
        reduce_pk<<<(BL * 96 / 4 + 255) / 256, 256, 0, stream>>>(
            partb, dblb, dblb16, BL * 96 / 4, BL * 96 / 4, SPX);

        // 4) dt_raw = dbl[:, :64] @ dtw^T  (2048 x 2048, K=64) -> bf16
        gemm_bf16<1, false><<<dim3(dinner / 128, BL / 64), 256, 0, stream>>>(
            dblb16, wb_dt_l, nullptr, dtrb16, BL, dinner, 64, 96, 64, dinner);

        // 5) chunked scan: local scans -> chunk prefix -> final pass
        scan_part1<16><<<scan_blocks, 256, 0, stream>>>(
            dtrb16, xcb16, dblb, dtb_l, alog_l, hendb, ssumb, Bsz, L, dinner, NC);
        chunk_prefix<64><<<pfx_blocks, 256, 0, stream>>>(
            hendb, ssumb, alog_l, Bsz, dinner);
        scan_part2<16><<<scan_blocks, 256, 0, stream>>>(
            dtrb16, xcb16, dblb, xzb16, dtb_l, alog_l, Dp_l, hendb,
            Bsz, L, dinner, NC);

        // 6) out = y @ ow^T      (2048 x 1024, K=2048), split-K x2 + reduce
        gemm_bf16<0, true><<<dim3(dmodel / 128, BL / 64, SPO), 256, 0, stream>>>(
            dtrb16, wb_ow_l, partb, nullptr, BL, dmodel, KSO, dinner, dinner, dmodel);
        if (l == 0)
            reduce_pk<<<(BL * dmodel / 4 + 255) / 256, 256, 0, stream>>>(
                partb, nullptr, curb, BL * dmodel / 4, BL * dmodel / 4, SPO);
        else
            reduce_pk<<<(BL * dmodel / 4 + 255) / 256, 256, 0, stream>>>(
                partb, out, nullptr, BL * dmodel / 4, BL * dmodel / 4, SPO);
    }
}